// Round 15
// baseline (254.417 us; speedup 1.0000x reference)
//
#include <hip/hip_runtime.h>
#include <math.h>

#define NTOK 8192
#define DDIM 256
#define KCB  4096
#define GEPS 1e-10f

typedef __attribute__((ext_vector_type(8))) short short8;   // 8 bf16 (4 VGPR)
typedef __attribute__((ext_vector_type(8))) unsigned short ushort8;
typedef __attribute__((ext_vector_type(4))) float f32x4;

// ws layout (float units)
#define WS_ESQ  0
#define WS_ZSQ  (WS_ESQ + KCB)          // 4096
#define WS_KEY  (WS_ZSQ + NTOK)         // 12288 (u64[8192])
#define WS_HIST (WS_KEY + 2 * NTOK)     // 28672
#define WS_COMM (WS_HIST + KCB)         // 32768
#define WS_ZH   32776                   // 16B-aligned
#define WS_END  (WS_ZH + (3 * NTOK * DDIM + 3 * KCB * DDIM) / 2)   // ≈ 19.01 MB

// plane strides/bases in USHORT units; K-step tiled layout:
// off = plane_base + kk*(NR*32) + r*32 + ss*8, ss = dh ^ ((r>>2)&3) baked in
#define PO_Z  (NTOK * DDIM)     // per-z-plane stride
#define PO_C  (KCB * DDIM)      // per-cb-plane stride
#define PO_CB (3 * NTOK * DDIM) // first cb plane

// out offsets (f32): z_q, embedding, indices, commitment, perplexity, entropy
#define OUT_ZQ   0
#define OUT_EMB  (NTOK * DDIM)
#define OUT_IDX  (2 * NTOK * DDIM)
#define OUT_SCAL (2 * NTOK * DDIM + NTOK)

// k_mfma tile geometry: 256 tokens x 128 codes, 4 waves (wave tile 128x64)
#define BTOK 256
#define BCODE 128

__device__ __forceinline__ unsigned short f2bf(float x) {   // RNE f32->bf16
  unsigned int u = __float_as_uint(x);
  u += 0x7FFFu + ((u >> 16) & 1u);
  return (unsigned short)(u >> 16);
}
__device__ __forceinline__ float bf2f(unsigned short h) {
  return __uint_as_float(((unsigned int)h) << 16);
}

__device__ __forceinline__ void gload16(const void* g, void* l) {
  __builtin_amdgcn_global_load_lds(
      (const __attribute__((address_space(1))) unsigned int*)g,
      (__attribute__((address_space(3))) unsigned int*)l, 16, 0, 0);
}

// ---------------- prep: e_sq/z_sq + K-tiled plane split (coalesced writes) ----------------
// grid 192 x 256: block = 64 rows (4 waves x 16 rows). Per (plane,kk) each wave
// writes one fully-contiguous 1KB run (lane l -> row r0+(l>>2), slot l&3).
__global__ __launch_bounds__(256) void k_prep(const float* __restrict__ cb,
                                              const float* __restrict__ z,
                                              float* __restrict__ esq,
                                              float* __restrict__ zsq,
                                              float* __restrict__ keyf,
                                              float* __restrict__ hist,
                                              float* __restrict__ comm,
                                              unsigned short* __restrict__ zh) {
  const int l   = threadIdx.x & 63;
  const int wid = threadIdx.x >> 6;
  const int r0  = blockIdx.x * 64 + wid * 16;       // wave-uniform, 16-aligned
  const int rl  = r0 + (l >> 2);                    // this lane's row (0..12287)
  const bool isc = rl < KCB;                        // whole wave same side (4096%16==0)
  const int r_in  = isc ? rl : rl - KCB;
  const int r0_in = isc ? r0 : r0 - KCB;
  const float* src = isc ? (cb + (size_t)rl * DDIM) : (z + (size_t)r_in * DDIM);
  const int ss = l & 3;
  const int dh = ss ^ ((r_in >> 2) & 3);            // bank-deswizzle baked in
  const unsigned NR      = isc ? (unsigned)KCB : (unsigned)NTOK;
  const unsigned pbase   = isc ? (unsigned)PO_CB : 0u;
  const unsigned pstride = isc ? (unsigned)PO_C : (unsigned)PO_Z;

  float ssum = 0.0f;
  #pragma unroll
  for (int kk = 0; kk < 8; ++kk) {
    const float4 va = *(const float4*)(src + kk * 32 + dh * 8);
    const float4 vb = *(const float4*)(src + kk * 32 + dh * 8 + 4);
    ssum += va.x * va.x + va.y * va.y + va.z * va.z + va.w * va.w
          + vb.x * vb.x + vb.y * vb.y + vb.z * vb.z + vb.w * vb.w;
    if (zh) {
      const float vv[8] = {va.x, va.y, va.z, va.w, vb.x, vb.y, vb.z, vb.w};
      ushort8 h8, m8, l8;
      #pragma unroll
      for (int e = 0; e < 8; ++e) {
        const float x  = vv[e];
        const unsigned short h = f2bf(x);
        const float r1 = x - bf2f(h);
        const unsigned short m = f2bf(r1);
        const float r2 = r1 - bf2f(m);
        h8[e] = h; m8[e] = m; l8[e] = f2bf(r2);
      }
      const unsigned off = pbase + (unsigned)kk * NR * 32 + (unsigned)r0_in * 32
                         + (unsigned)l * 8;          // 64 lanes -> 1KB contiguous
      *(ushort8*)(zh + off)                = h8;
      *(ushort8*)(zh + off + pstride)      = m8;
      *(ushort8*)(zh + off + 2 * pstride)  = l8;
    }
  }
  ssum += __shfl_xor(ssum, 1);
  ssum += __shfl_xor(ssum, 2);
  if ((l & 3) == 0) {
    if (isc) esq[rl] = ssum;
    else     zsq[r_in] = ssum;
  }

  const int gid = blockIdx.x * 256 + threadIdx.x;   // 49152 >= 16384+4096+1
  if (gid < 2 * NTOK) keyf[gid] = 0.0f;
  else if (gid < 2 * NTOK + KCB) hist[gid - 2 * NTOK] = 0.0f;
  else if (gid == 2 * NTOK + KCB) comm[0] = 0.0f;
}

// ---------------- LDS-staged split-bf16 MFMA GEMM, 256x128 tile ----------------
// 1-D grid 1024, 256 threads = 4 waves, wave tile 128x64, BK=32.
// LDS 72KB (A 3x16KB + B 3x8KB) -> 2 blocks/CU. Staging: 72 x 1KB contiguous runs.
__global__ __launch_bounds__(256, 2) void k_mfma(const unsigned short* __restrict__ zh,
                                                 const float* __restrict__ u,
                                                 const float* __restrict__ esq,
                                                 const float* __restrict__ zsq,
                                                 unsigned long long* __restrict__ key) {
  __shared__ __align__(1024) unsigned char lbuf[73728];

  const int tid = threadIdx.x;
  const int l   = tid & 63;
  const int wid = tid >> 6;

  // bijective XCD-compact swizzle (1024 % 8 == 0): each XCD gets 4 code tiles x 32 tok tiles
  const int bid = blockIdx.x;
  const int xcd = bid & 7;
  const int loc = bid >> 3;                 // 0..127
  const int cx  = xcd * 4 + (loc & 3);      // code tile 0..31
  const int cy  = loc >> 2;                 // token tile 0..31
  const int tok0 = cy * BTOK;
  const int c0   = cx * BCODE;

  const int lrow = l & 15;
  const int lkg  = l >> 4;                  // 0..3
  const int tw = (wid >> 1) * 128;          // wave token base (0/128)
  const int cw = (wid & 1) * 64;            // wave code base (0/64)

  // staging: 72 chunks of 1KB (A: 3 planes x 16 subtiles; B: 3 planes x 8)
  unsigned int srcoff[18], lbase[18];
  #pragma unroll
  for (int j = 0; j < 18; ++j) {
    const int c = wid + 4 * j;              // 0..71
    unsigned int off, lb;
    if (c < 48) {                           // A
      const int p = c >> 4, sub = c & 15;
      off = (unsigned)p * PO_Z + (unsigned)tok0 * 32 + (unsigned)sub * 512;
      lb  = (unsigned)(p * 16384 + sub * 1024);
    } else {                                // B
      const int q = c - 48;
      const int p = q >> 3, sub = q & 7;
      off = (unsigned)PO_CB + (unsigned)p * PO_C + (unsigned)c0 * 32
          + (unsigned)sub * 512;
      lb  = (unsigned)(49152 + p * 8192 + sub * 1024);
    }
    srcoff[j] = off + (unsigned)l * 8;
    lbase[j]  = lb;
  }

  f32x4 acc[8][4] = {};
  const unsigned int sw = ((unsigned int)(lkg ^ ((lrow >> 2) & 3))) << 4;
  const int rb = lkg * 4;

  for (int kk = 0; kk < 8; ++kk) {
    const unsigned int ka = (unsigned)kk * (NTOK * 32);
    const unsigned int kb = (unsigned)kk * (KCB * 32);
    __syncthreads();                        // previous step fully consumed
    #pragma unroll
    for (int j = 0; j < 12; ++j)  gload16(zh + srcoff[j] + ka, lbuf + lbase[j]);
    #pragma unroll
    for (int j = 12; j < 18; ++j) gload16(zh + srcoff[j] + kb, lbuf + lbase[j]);
    __syncthreads();                        // vmcnt drain; other block overlaps

    short8 bfr[3][4];
    #pragma unroll
    for (int ni = 0; ni < 4; ++ni) {
      const unsigned int boff = (unsigned int)(cw + ni * 16 + lrow) * 64 + sw;
      bfr[0][ni] = *(const short8*)(lbuf + 49152 + boff);   // bh
      bfr[1][ni] = *(const short8*)(lbuf + 57344 + boff);   // bm
      bfr[2][ni] = *(const short8*)(lbuf + 65536 + boff);   // bl
    }
    #pragma unroll
    for (int mi = 0; mi < 8; ++mi) {
      const unsigned int aoff = (unsigned int)(tw + mi * 16 + lrow) * 64 + sw;
      const short8 ah = *(const short8*)(lbuf + 0     + aoff);
      const short8 am = *(const short8*)(lbuf + 16384 + aoff);
      const short8 al = *(const short8*)(lbuf + 32768 + aoff);
      #pragma unroll
      for (int ni = 0; ni < 4; ++ni) {
        f32x4 a = acc[mi][ni];
        a = __builtin_amdgcn_mfma_f32_16x16x32_bf16(am, bfr[1][ni], a, 0, 0, 0); // mm
        a = __builtin_amdgcn_mfma_f32_16x16x32_bf16(ah, bfr[2][ni], a, 0, 0, 0); // hl
        a = __builtin_amdgcn_mfma_f32_16x16x32_bf16(al, bfr[0][ni], a, 0, 0, 0); // lh
        a = __builtin_amdgcn_mfma_f32_16x16x32_bf16(ah, bfr[1][ni], a, 0, 0, 0); // hm
        a = __builtin_amdgcn_mfma_f32_16x16x32_bf16(am, bfr[0][ni], a, 0, 0, 0); // mh
        a = __builtin_amdgcn_mfma_f32_16x16x32_bf16(ah, bfr[0][ni], a, 0, 0, 0); // hh
        acc[mi][ni] = a;
      }
    }
  }

  // ---- epilogue: gumbel + score + argmax. C/D: col=l&15, row=(l>>4)*4+reg ----
  float esv[4];
  #pragma unroll
  for (int ni = 0; ni < 4; ++ni) esv[ni] = esq[c0 + cw + ni * 16 + lrow];

  #pragma unroll
  for (int mi = 0; mi < 8; ++mi) {
    #pragma unroll
    for (int r = 0; r < 4; ++r) {
      const int t  = tok0 + tw + mi * 16 + rb + r;
      const float zq = zsq[t];
      float bv = -3.402823e38f;
      int   bc = c0 + cw + lrow;
      #pragma unroll
      for (int ni = 0; ni < 4; ++ni) {
        const int c = c0 + cw + ni * 16 + lrow;
        const float uu = u[(size_t)t * KCB + c];
        const float g  = -logf(-logf(uu + GEPS) + GEPS);
        const float sc = -((zq + esv[ni]) - 2.0f * acc[mi][ni][r]) + g;
        if (sc > bv) { bv = sc; bc = c; }        // ni ascending = code ascending
      }
      #pragma unroll
      for (int m = 1; m < 16; m <<= 1) {
        const float ov = __shfl_xor(bv, m);
        const int   oc = __shfl_xor(bc, m);
        if (ov > bv || (ov == bv && oc < bc)) { bv = ov; bc = oc; }
      }
      if (lrow == 0) {
        unsigned int b = __float_as_uint(bv);
        b = (b & 0x80000000u) ? ~b : (b | 0x80000000u);
        const unsigned long long kk2 =
            ((unsigned long long)b << 32) | (unsigned int)(KCB - 1 - bc);
        atomicMax(&key[t], kk2);
      }
    }
  }
}

// ---------------- fallback f32 path (used only if ws too small) ----------------
#define BT 128
#define BK 128
#define DC 32
#define PS 132
__global__ __launch_bounds__(256) void k_score(const float* __restrict__ z,
                                               const float* __restrict__ u,
                                               const float* __restrict__ cb,
                                               const float* __restrict__ esq,
                                               const float* __restrict__ zsq,
                                               unsigned long long* __restrict__ key) {
  __shared__ float zsm[DC][PS];
  __shared__ float csm[DC][PS];
  const int tid  = threadIdx.x;
  const int tok0 = blockIdx.x * BT;
  const int kb   = blockIdx.y * BK;
  const int tx = tid & 15;
  const int ty = tid >> 4;
  const int srow = tid >> 3;
  const int sc4  = (tid & 7) * 4;
  float acc[8][8] = {};
  float4 zr[4], cr[4];
  #pragma unroll
  for (int j = 0; j < 4; ++j) {
    const int r = srow + 32 * j;
    zr[j] = *(const float4*)(z  + (size_t)(tok0 + r) * DDIM + sc4);
    cr[j] = *(const float4*)(cb + (size_t)(kb  + r) * DDIM + sc4);
  }
  for (int dc = 0; dc < DDIM / DC; ++dc) {
    __syncthreads();
    #pragma unroll
    for (int j = 0; j < 4; ++j) {
      const int r = srow + 32 * j;
      zsm[sc4 + 0][r] = zr[j].x; zsm[sc4 + 1][r] = zr[j].y;
      zsm[sc4 + 2][r] = zr[j].z; zsm[sc4 + 3][r] = zr[j].w;
      csm[sc4 + 0][r] = cr[j].x; csm[sc4 + 1][r] = cr[j].y;
      csm[sc4 + 2][r] = cr[j].z; csm[sc4 + 3][r] = cr[j].w;
    }
    __syncthreads();
    if (dc + 1 < DDIM / DC) {
      const int d0 = (dc + 1) * DC;
      #pragma unroll
      for (int j = 0; j < 4; ++j) {
        const int r = srow + 32 * j;
        zr[j] = *(const float4*)(z  + (size_t)(tok0 + r) * DDIM + d0 + sc4);
        cr[j] = *(const float4*)(cb + (size_t)(kb  + r) * DDIM + d0 + sc4);
      }
    }
    #pragma unroll 4
    for (int d = 0; d < DC; ++d) {
      const float4 za = *(const float4*)&zsm[d][8 * ty];
      const float4 zb = *(const float4*)&zsm[d][8 * ty + 4];
      const float4 ca = *(const float4*)&csm[d][8 * tx];
      const float4 cc = *(const float4*)&csm[d][8 * tx + 4];
      const float zf[8] = {za.x, za.y, za.z, za.w, zb.x, zb.y, zb.z, zb.w};
      const float cf[8] = {ca.x, ca.y, ca.z, ca.w, cc.x, cc.y, cc.z, cc.w};
      #pragma unroll
      for (int i = 0; i < 8; ++i)
        #pragma unroll
        for (int j = 0; j < 8; ++j) acc[i][j] += zf[i] * cf[j];
    }
  }
  const float4 ea = *(const float4*)(esq + kb + 8 * tx);
  const float4 eb = *(const float4*)(esq + kb + 8 * tx + 4);
  const float esa[8] = {ea.x, ea.y, ea.z, ea.w, eb.x, eb.y, eb.z, eb.w};
  float bv[8]; int bj[8];
  #pragma unroll
  for (int i = 0; i < 8; ++i) {
    const int tok = tok0 + 8 * ty + i;
    const float zq = zsq[tok];
    const float4 ua = *(const float4*)(u + (size_t)tok * KCB + kb + 8 * tx);
    const float4 ub = *(const float4*)(u + (size_t)tok * KCB + kb + 8 * tx + 4);
    const float uu[8] = {ua.x, ua.y, ua.z, ua.w, ub.x, ub.y, ub.z, ub.w};
    bv[i] = -3.402823e38f; bj[i] = kb + 8 * tx;
    #pragma unroll
    for (int j = 0; j < 8; ++j) {
      const float g = -logf(-logf(uu[j] + GEPS) + GEPS);
      const float s = -((zq + esa[j]) - 2.0f * acc[i][j]) + g;
      if (s > bv[i]) { bv[i] = s; bj[i] = kb + 8 * tx + j; }
    }
  }
  __syncthreads();
  float* pv = &zsm[0][0];
  int*   pi = (int*)&csm[0][0];
  #pragma unroll
  for (int i = 0; i < 8; ++i) {
    pv[(8 * ty + i) * 16 + tx] = bv[i];
    pi[(8 * ty + i) * 16 + tx] = bj[i];
  }
  __syncthreads();
  if (tid < BT) {
    float best  = pv[tid * 16];
    int   besti = pi[tid * 16];
    for (int x = 1; x < 16; ++x) {
      const float v = pv[tid * 16 + x];
      if (v > best) { best = v; besti = pi[tid * 16 + x]; }
    }
    unsigned int b = __float_as_uint(best);
    b = (b & 0x80000000u) ? ~b : (b | 0x80000000u);
    const unsigned long long kk =
        ((unsigned long long)b << 32) | (unsigned int)(KCB - 1 - besti);
    atomicMax(&key[tok0 + tid], kk);
  }
}

// ---------------- finalize per token ----------------
__global__ __launch_bounds__(256) void k_final(const float* __restrict__ z,
                                               const float* __restrict__ cb,
                                               const unsigned long long* __restrict__ key,
                                               float* __restrict__ out,
                                               float* __restrict__ hist,
                                               float* __restrict__ comm) {
  const int lane = threadIdx.x & 63;
  const int wv   = threadIdx.x >> 6;
  const int tok  = blockIdx.x * 4 + wv;
  const unsigned long long kk = key[tok];
  int bi = KCB - 1 - (int)(kk & 0xFFFFFFFFu);
  bi = min(max(bi, 0), KCB - 1);
  const float4 c  = *(const float4*)(cb + (size_t)bi * DDIM + 4 * lane);
  const float4 zv = *(const float4*)(z + (size_t)tok * DDIM + 4 * lane);
  float4 q;
  q.x = zv.x + (c.x - zv.x);
  q.y = zv.y + (c.y - zv.y);
  q.z = zv.z + (c.z - zv.z);
  q.w = zv.w + (c.w - zv.w);
  const size_t o = (size_t)tok * DDIM + 4 * lane;
  *(float4*)(out + OUT_ZQ  + o) = q;
  *(float4*)(out + OUT_EMB + o) = c;
  const float dx = q.x - zv.x, dy = q.y - zv.y, dz = q.z - zv.z, dw = q.w - zv.w;
  float s = dx * dx + dy * dy + dz * dz + dw * dw;
  #pragma unroll
  for (int o2 = 32; o2 > 0; o2 >>= 1) s += __shfl_down(s, o2);
  if (lane == 0) {
    atomicAdd(comm, s);
    atomicAdd(&hist[bi], 1.0f);
    out[OUT_IDX + tok] = (float)bi;
  }
}

// ---------------- scalars ----------------
__global__ __launch_bounds__(1024) void k_scal(const float* __restrict__ cu,
                                               const float* __restrict__ hist,
                                               const float* __restrict__ comm,
                                               float* __restrict__ out) {
  __shared__ float red[1024];
  const int tid = threadIdx.x;
  float us[4];
  float s = 0.0f;
  #pragma unroll
  for (int j = 0; j < 4; ++j) {
    const int k = tid * 4 + j;
    us[j] = cu[k] * 0.99f + hist[k];
    s += us[j];
  }
  red[tid] = s; __syncthreads();
  for (int o = 512; o > 0; o >>= 1) {
    if (tid < o) red[tid] += red[tid + o];
    __syncthreads();
  }
  const float usum = red[0];
  __syncthreads();
  float e = 0.0f;
  #pragma unroll
  for (int j = 0; j < 4; ++j) {
    const float p = (usum > 0.0f) ? (us[j] / (usum + GEPS)) : (1.0f / (float)KCB);
    e -= p * logf(p + GEPS);
  }
  red[tid] = e; __syncthreads();
  for (int o = 512; o > 0; o >>= 1) {
    if (tid < o) red[tid] += red[tid + o];
    __syncthreads();
  }
  if (tid == 0) {
    const float entropy = red[0];
    out[OUT_SCAL + 0] = comm[0] / (float)((size_t)NTOK * DDIM);
    out[OUT_SCAL + 1] = expf(entropy);
    out[OUT_SCAL + 2] = entropy;
  }
}

extern "C" void kernel_launch(void* const* d_in, const int* in_sizes, int n_in,
                              void* d_out, int out_size, void* d_ws, size_t ws_size,
                              hipStream_t stream) {
  const float* z  = (const float*)d_in[0];
  const float* u  = (const float*)d_in[1];
  const float* cb = (const float*)d_in[2];
  const float* cu = (const float*)d_in[3];

  float* ws   = (float*)d_ws;
  float* esq  = ws + WS_ESQ;
  float* zsq  = ws + WS_ZSQ;
  float* keyf = ws + WS_KEY;
  unsigned long long* key = (unsigned long long*)keyf;
  float* hist = ws + WS_HIST;
  float* comm = ws + WS_COMM;
  float* out  = (float*)d_out;

  if (ws_size >= (size_t)WS_END * 4) {
    unsigned short* zh = (unsigned short*)(ws + WS_ZH);
    k_prep<<<dim3((KCB + NTOK) / 64), dim3(256), 0, stream>>>(
        cb, z, esq, zsq, keyf, hist, comm, zh);
    k_mfma<<<dim3((NTOK / BTOK) * (KCB / BCODE)), dim3(256), 0, stream>>>(
        zh, u, esq, zsq, key);
  } else {
    k_prep<<<dim3((KCB + NTOK) / 64), dim3(256), 0, stream>>>(
        cb, z, esq, zsq, keyf, hist, comm, (unsigned short*)nullptr);
    k_score<<<dim3(NTOK / BT, KCB / BK), dim3(256), 0, stream>>>(z, u, cb, esq, zsq, key);
  }

  k_final<<<dim3(NTOK / 4), dim3(256), 0, stream>>>(z, cb, key, out, hist, comm);
  k_scal <<<dim3(1), dim3(1024), 0, stream>>>(cu, hist, comm, out);
}

// Round 16
// 176.810 us; speedup vs baseline: 1.4389x; 1.4389x over previous
//
#include <hip/hip_runtime.h>
#include <math.h>

#define NTOK 8192
#define DDIM 256
#define KCB  4096
#define GEPS 1e-10f

typedef __attribute__((ext_vector_type(8))) short short8;   // 8 bf16 (4 VGPR)
typedef __attribute__((ext_vector_type(8))) unsigned short ushort8;
typedef __attribute__((ext_vector_type(4))) float f32x4;

// ws layout (float units)
#define WS_ESQ  0
#define WS_ZSQ  (WS_ESQ + KCB)          // 4096
#define WS_KEY  (WS_ZSQ + NTOK)         // 12288 (u64[8192])
#define WS_HIST (WS_KEY + 2 * NTOK)     // 28672
#define WS_COMM (WS_HIST + KCB)         // 32768
#define WS_ZH   32776                   // 16B-aligned
#define WS_END  (WS_ZH + (3 * NTOK * DDIM + 3 * KCB * DDIM) / 2)   // ≈ 19.01 MB

// plane strides/bases in USHORT units; K-step tiled layout:
// off = plane_base + kk*(NR*32) + r*32 + ss*8, ss = dh ^ ((r>>2)&3) baked in
#define PO_Z  (NTOK * DDIM)     // per-z-plane stride
#define PO_C  (KCB * DDIM)      // per-cb-plane stride
#define PO_CB (3 * NTOK * DDIM) // first cb plane

// out offsets (f32): z_q, embedding, indices, commitment, perplexity, entropy
#define OUT_ZQ   0
#define OUT_EMB  (NTOK * DDIM)
#define OUT_IDX  (2 * NTOK * DDIM)
#define OUT_SCAL (2 * NTOK * DDIM + NTOK)

__device__ __forceinline__ unsigned short f2bf(float x) {   // RNE f32->bf16
  unsigned int u = __float_as_uint(x);
  u += 0x7FFFu + ((u >> 16) & 1u);
  return (unsigned short)(u >> 16);
}
__device__ __forceinline__ float bf2f(unsigned short h) {
  return __uint_as_float(((unsigned int)h) << 16);
}

__device__ __forceinline__ void gload16(const void* g, void* l) {
  __builtin_amdgcn_global_load_lds(
      (const __attribute__((address_space(1))) unsigned int*)g,
      (__attribute__((address_space(3))) unsigned int*)l, 16, 0, 0);
}

// ---------------- prep: e_sq/z_sq + K-tiled plane split (coalesced, R15) ----------------
// grid 192 x 256: block = 64 rows (4 waves x 16 rows). Per (plane,kk) each wave
// writes one fully-contiguous 1KB run (lane l -> row r0+(l>>2), slot l&3).
__global__ __launch_bounds__(256) void k_prep(const float* __restrict__ cb,
                                              const float* __restrict__ z,
                                              float* __restrict__ esq,
                                              float* __restrict__ zsq,
                                              float* __restrict__ keyf,
                                              float* __restrict__ hist,
                                              float* __restrict__ comm,
                                              unsigned short* __restrict__ zh) {
  const int l   = threadIdx.x & 63;
  const int wid = threadIdx.x >> 6;
  const int r0  = blockIdx.x * 64 + wid * 16;       // wave-uniform, 16-aligned
  const int rl  = r0 + (l >> 2);                    // this lane's row (0..12287)
  const bool isc = rl < KCB;                        // whole wave same side
  const int r_in  = isc ? rl : rl - KCB;
  const int r0_in = isc ? r0 : r0 - KCB;
  const float* src = isc ? (cb + (size_t)rl * DDIM) : (z + (size_t)r_in * DDIM);
  const int ss = l & 3;
  const int dh = ss ^ ((r_in >> 2) & 3);            // bank-deswizzle baked in
  const unsigned NR      = isc ? (unsigned)KCB : (unsigned)NTOK;
  const unsigned pbase   = isc ? (unsigned)PO_CB : 0u;
  const unsigned pstride = isc ? (unsigned)PO_C : (unsigned)PO_Z;

  float ssum = 0.0f;
  #pragma unroll
  for (int kk = 0; kk < 8; ++kk) {
    const float4 va = *(const float4*)(src + kk * 32 + dh * 8);
    const float4 vb = *(const float4*)(src + kk * 32 + dh * 8 + 4);
    ssum += va.x * va.x + va.y * va.y + va.z * va.z + va.w * va.w
          + vb.x * vb.x + vb.y * vb.y + vb.z * vb.z + vb.w * vb.w;
    if (zh) {
      const float vv[8] = {va.x, va.y, va.z, va.w, vb.x, vb.y, vb.z, vb.w};
      ushort8 h8, m8, l8;
      #pragma unroll
      for (int e = 0; e < 8; ++e) {
        const float x  = vv[e];
        const unsigned short h = f2bf(x);
        const float r1 = x - bf2f(h);
        const unsigned short m = f2bf(r1);
        const float r2 = r1 - bf2f(m);
        h8[e] = h; m8[e] = m; l8[e] = f2bf(r2);
      }
      const unsigned off = pbase + (unsigned)kk * NR * 32 + (unsigned)r0_in * 32
                         + (unsigned)l * 8;          // 64 lanes -> 1KB contiguous
      *(ushort8*)(zh + off)                = h8;
      *(ushort8*)(zh + off + pstride)      = m8;
      *(ushort8*)(zh + off + 2 * pstride)  = l8;
    }
  }
  ssum += __shfl_xor(ssum, 1);
  ssum += __shfl_xor(ssum, 2);
  if ((l & 3) == 0) {
    if (isc) esq[rl] = ssum;
    else     zsq[r_in] = ssum;
  }

  const int gid = blockIdx.x * 256 + threadIdx.x;   // 49152 >= 16384+4096+1
  if (gid < 2 * NTOK) keyf[gid] = 0.0f;
  else if (gid < 2 * NTOK + KCB) hist[gid - 2 * NTOK] = 0.0f;
  else if (gid == 2 * NTOK + KCB) comm[0] = 0.0f;
}

// ---------------- pipelined split-bf16 MFMA GEMM (R12 phases + R14 staging) ----------------
// 1-D grid 2048, 256 threads = 4 waves (2x2), tile 128x128, BK=32, 48KB LDS.
// Per step: [vmcnt(0)+bar] -> 24 ds_read frags -> [lgkmcnt(0)+bar] ->
// issue next stage (12 contiguous 1KB gload_lds, in flight across MFMA) -> 96 MFMA.
__global__ __launch_bounds__(256, 2) void k_mfma(const unsigned short* __restrict__ zh,
                                                 const float* __restrict__ u,
                                                 const float* __restrict__ esq,
                                                 const float* __restrict__ zsq,
                                                 unsigned long long* __restrict__ key) {
  __shared__ __align__(1024) unsigned char lbuf[49152];

  const int tid = threadIdx.x;
  const int l   = tid & 63;
  const int wid = tid >> 6;

  // bijective XCD-compact swizzle (2048 % 8 == 0)
  const int bid = blockIdx.x;
  const int s   = (bid & 7) * 256 + (bid >> 3);   // contiguous 256-block chunk per XCD
  const int cx  = ((s >> 8) << 2) + (s & 3);      // code tile 0..31
  const int cy  = (s & 255) >> 2;                 // token tile 0..63
  const int tok0 = cy * 128;
  const int c0   = cx * 128;

  const int lrow = l & 15;
  const int lkg  = l >> 4;                  // 0..3
  const int tw = (wid >> 1) * 64;           // wave token base
  const int cw = (wid & 1) * 64;            // wave code base

  // staging: 48 chunks of 1KB fully contiguous (K-tiled planes); 12 per wave
  unsigned int srcoff[12], lbase[12];
  #pragma unroll
  for (int j = 0; j < 12; ++j) {
    const int c = wid + 4 * j;              // 0..47
    unsigned int off, lb;
    if (j < 6) {                            // A: 3 planes x 8 subtiles
      const int p = c >> 3, sub = c & 7;
      off = (unsigned)p * PO_Z + (unsigned)tok0 * 32 + (unsigned)sub * 512;
      lb  = (unsigned)(p * 8192 + sub * 1024);
    } else {                                // B: 3 planes x 8 subtiles
      const int q = c - 24;
      const int p = q >> 3, sub = q & 7;
      off = (unsigned)PO_CB + (unsigned)p * PO_C + (unsigned)c0 * 32
          + (unsigned)sub * 512;
      lb  = (unsigned)(24576 + p * 8192 + sub * 1024);
    }
    srcoff[j] = off + (unsigned)l * 8;
    lbase[j]  = lb;
  }

  f32x4 acc[4][4] = {};
  const unsigned int sw = ((unsigned int)(lkg ^ ((lrow >> 2) & 3))) << 4;
  const int rb = lkg * 4;

  // prologue: stage K-step 0
  #pragma unroll
  for (int j = 0; j < 6; ++j)  gload16(zh + srcoff[j], lbuf + lbase[j]);
  #pragma unroll
  for (int j = 6; j < 12; ++j) gload16(zh + srcoff[j], lbuf + lbase[j]);

  #pragma unroll
  for (int kk = 0; kk < 8; ++kk) {
    // (1) this step's stage loads were issued one full MFMA phase ago
    asm volatile("s_waitcnt vmcnt(0)" ::: "memory");
    __builtin_amdgcn_sched_barrier(0);
    __builtin_amdgcn_s_barrier();
    __builtin_amdgcn_sched_barrier(0);

    // (2) all fragments -> registers
    short8 ah[4], am[4], al[4], bh[4], bm[4], bl[4];
    #pragma unroll
    for (int ni = 0; ni < 4; ++ni) {
      const unsigned int boff = (unsigned int)(cw + ni * 16 + lrow) * 64 + sw;
      bh[ni] = *(const short8*)(lbuf + 24576 + boff);
      bm[ni] = *(const short8*)(lbuf + 32768 + boff);
      bl[ni] = *(const short8*)(lbuf + 40960 + boff);
    }
    #pragma unroll
    for (int mi = 0; mi < 4; ++mi) {
      const unsigned int aoff = (unsigned int)(tw + mi * 16 + lrow) * 64 + sw;
      ah[mi] = *(const short8*)(lbuf + 0     + aoff);
      am[mi] = *(const short8*)(lbuf + 8192  + aoff);
      al[mi] = *(const short8*)(lbuf + 16384 + aoff);
    }

    // (3) everyone's reads landed in regs -> buffer free for overwrite
    asm volatile("s_waitcnt lgkmcnt(0)" ::: "memory");
    __builtin_amdgcn_sched_barrier(0);
    __builtin_amdgcn_s_barrier();
    __builtin_amdgcn_sched_barrier(0);

    // (4) issue next stage; stays in flight across the MFMA phase below
    if (kk < 7) {
      const unsigned int ka = (unsigned)(kk + 1) * (NTOK * 32);
      const unsigned int kb = (unsigned)(kk + 1) * (KCB * 32);
      #pragma unroll
      for (int j = 0; j < 6; ++j)  gload16(zh + srcoff[j] + ka, lbuf + lbase[j]);
      #pragma unroll
      for (int j = 6; j < 12; ++j) gload16(zh + srcoff[j] + kb, lbuf + lbase[j]);
    }
    __builtin_amdgcn_sched_barrier(0);

    // (5) 96 MFMAs from registers (6-term chain, order identical to R6-R15)
    __builtin_amdgcn_s_setprio(1);
    #pragma unroll
    for (int mi = 0; mi < 4; ++mi) {
      #pragma unroll
      for (int ni = 0; ni < 4; ++ni) {
        f32x4 a = acc[mi][ni];
        a = __builtin_amdgcn_mfma_f32_16x16x32_bf16(am[mi], bm[ni], a, 0, 0, 0); // mm
        a = __builtin_amdgcn_mfma_f32_16x16x32_bf16(ah[mi], bl[ni], a, 0, 0, 0); // hl
        a = __builtin_amdgcn_mfma_f32_16x16x32_bf16(al[mi], bh[ni], a, 0, 0, 0); // lh
        a = __builtin_amdgcn_mfma_f32_16x16x32_bf16(ah[mi], bm[ni], a, 0, 0, 0); // hm
        a = __builtin_amdgcn_mfma_f32_16x16x32_bf16(am[mi], bh[ni], a, 0, 0, 0); // mh
        a = __builtin_amdgcn_mfma_f32_16x16x32_bf16(ah[mi], bh[ni], a, 0, 0, 0); // hh
        acc[mi][ni] = a;
      }
    }
    __builtin_amdgcn_s_setprio(0);
    __builtin_amdgcn_sched_barrier(0);
  }

  // ---- epilogue: gumbel + score + argmax. C/D: col=l&15, row=(l>>4)*4+reg ----
  float esv[4];
  #pragma unroll
  for (int ni = 0; ni < 4; ++ni) esv[ni] = esq[c0 + cw + ni * 16 + lrow];

  #pragma unroll
  for (int mi = 0; mi < 4; ++mi) {
    #pragma unroll
    for (int r = 0; r < 4; ++r) {
      const int t  = tok0 + tw + mi * 16 + rb + r;
      const float zq = zsq[t];
      float bv = -3.402823e38f;
      int   bc = c0 + cw + lrow;
      #pragma unroll
      for (int ni = 0; ni < 4; ++ni) {
        const int c = c0 + cw + ni * 16 + lrow;
        const float uu = u[(size_t)t * KCB + c];
        const float g  = -logf(-logf(uu + GEPS) + GEPS);
        const float sc = -((zq + esv[ni]) - 2.0f * acc[mi][ni][r]) + g;
        if (sc > bv) { bv = sc; bc = c; }        // ni ascending = code ascending
      }
      #pragma unroll
      for (int m = 1; m < 16; m <<= 1) {
        const float ov = __shfl_xor(bv, m);
        const int   oc = __shfl_xor(bc, m);
        if (ov > bv || (ov == bv && oc < bc)) { bv = ov; bc = oc; }
      }
      if (lrow == 0) {
        unsigned int b = __float_as_uint(bv);
        b = (b & 0x80000000u) ? ~b : (b | 0x80000000u);
        const unsigned long long kk2 =
            ((unsigned long long)b << 32) | (unsigned int)(KCB - 1 - bc);
        atomicMax(&key[t], kk2);
      }
    }
  }
}

// ---------------- fallback f32 path (used only if ws too small) ----------------
#define BT 128
#define BK 128
#define DC 32
#define PS 132
__global__ __launch_bounds__(256) void k_score(const float* __restrict__ z,
                                               const float* __restrict__ u,
                                               const float* __restrict__ cb,
                                               const float* __restrict__ esq,
                                               const float* __restrict__ zsq,
                                               unsigned long long* __restrict__ key) {
  __shared__ float zsm[DC][PS];
  __shared__ float csm[DC][PS];
  const int tid  = threadIdx.x;
  const int tok0 = blockIdx.x * BT;
  const int kb   = blockIdx.y * BK;
  const int tx = tid & 15;
  const int ty = tid >> 4;
  const int srow = tid >> 3;
  const int sc4  = (tid & 7) * 4;
  float acc[8][8] = {};
  float4 zr[4], cr[4];
  #pragma unroll
  for (int j = 0; j < 4; ++j) {
    const int r = srow + 32 * j;
    zr[j] = *(const float4*)(z  + (size_t)(tok0 + r) * DDIM + sc4);
    cr[j] = *(const float4*)(cb + (size_t)(kb  + r) * DDIM + sc4);
  }
  for (int dc = 0; dc < DDIM / DC; ++dc) {
    __syncthreads();
    #pragma unroll
    for (int j = 0; j < 4; ++j) {
      const int r = srow + 32 * j;
      zsm[sc4 + 0][r] = zr[j].x; zsm[sc4 + 1][r] = zr[j].y;
      zsm[sc4 + 2][r] = zr[j].z; zsm[sc4 + 3][r] = zr[j].w;
      csm[sc4 + 0][r] = cr[j].x; csm[sc4 + 1][r] = cr[j].y;
      csm[sc4 + 2][r] = cr[j].z; csm[sc4 + 3][r] = cr[j].w;
    }
    __syncthreads();
    if (dc + 1 < DDIM / DC) {
      const int d0 = (dc + 1) * DC;
      #pragma unroll
      for (int j = 0; j < 4; ++j) {
        const int r = srow + 32 * j;
        zr[j] = *(const float4*)(z  + (size_t)(tok0 + r) * DDIM + d0 + sc4);
        cr[j] = *(const float4*)(cb + (size_t)(kb  + r) * DDIM + d0 + sc4);
      }
    }
    #pragma unroll 4
    for (int d = 0; d < DC; ++d) {
      const float4 za = *(const float4*)&zsm[d][8 * ty];
      const float4 zb = *(const float4*)&zsm[d][8 * ty + 4];
      const float4 ca = *(const float4*)&csm[d][8 * tx];
      const float4 cc = *(const float4*)&csm[d][8 * tx + 4];
      const float zf[8] = {za.x, za.y, za.z, za.w, zb.x, zb.y, zb.z, zb.w};
      const float cf[8] = {ca.x, ca.y, ca.z, ca.w, cc.x, cc.y, cc.z, cc.w};
      #pragma unroll
      for (int i = 0; i < 8; ++i)
        #pragma unroll
        for (int j = 0; j < 8; ++j) acc[i][j] += zf[i] * cf[j];
    }
  }
  const float4 ea = *(const float4*)(esq + kb + 8 * tx);
  const float4 eb = *(const float4*)(esq + kb + 8 * tx + 4);
  const float esa[8] = {ea.x, ea.y, ea.z, ea.w, eb.x, eb.y, eb.z, eb.w};
  float bv[8]; int bj[8];
  #pragma unroll
  for (int i = 0; i < 8; ++i) {
    const int tok = tok0 + 8 * ty + i;
    const float zq = zsq[tok];
    const float4 ua = *(const float4*)(u + (size_t)tok * KCB + kb + 8 * tx);
    const float4 ub = *(const float4*)(u + (size_t)tok * KCB + kb + 8 * tx + 4);
    const float uu[8] = {ua.x, ua.y, ua.z, ua.w, ub.x, ub.y, ub.z, ub.w};
    bv[i] = -3.402823e38f; bj[i] = kb + 8 * tx;
    #pragma unroll
    for (int j = 0; j < 8; ++j) {
      const float g = -logf(-logf(uu[j] + GEPS) + GEPS);
      const float s = -((zq + esa[j]) - 2.0f * acc[i][j]) + g;
      if (s > bv[i]) { bv[i] = s; bj[i] = kb + 8 * tx + j; }
    }
  }
  __syncthreads();
  float* pv = &zsm[0][0];
  int*   pi = (int*)&csm[0][0];
  #pragma unroll
  for (int i = 0; i < 8; ++i) {
    pv[(8 * ty + i) * 16 + tx] = bv[i];
    pi[(8 * ty + i) * 16 + tx] = bj[i];
  }
  __syncthreads();
  if (tid < BT) {
    float best  = pv[tid * 16];
    int   besti = pi[tid * 16];
    for (int x = 1; x < 16; ++x) {
      const float v = pv[tid * 16 + x];
      if (v > best) { best = v; besti = pi[tid * 16 + x]; }
    }
    unsigned int b = __float_as_uint(best);
    b = (b & 0x80000000u) ? ~b : (b | 0x80000000u);
    const unsigned long long kk =
        ((unsigned long long)b << 32) | (unsigned int)(KCB - 1 - besti);
    atomicMax(&key[tok0 + tid], kk);
  }
}

// ---------------- finalize per token ----------------
__global__ __launch_bounds__(256) void k_final(const float* __restrict__ z,
                                               const float* __restrict__ cb,
                                               const unsigned long long* __restrict__ key,
                                               float* __restrict__ out,
                                               float* __restrict__ hist,
                                               float* __restrict__ comm) {
  __shared__ float cred[4];
  const int lane = threadIdx.x & 63;
  const int wv   = threadIdx.x >> 6;
  const int tok  = blockIdx.x * 4 + wv;
  const unsigned long long kk = key[tok];
  int bi = KCB - 1 - (int)(kk & 0xFFFFFFFFu);
  bi = min(max(bi, 0), KCB - 1);
  const float4 c  = *(const float4*)(cb + (size_t)bi * DDIM + 4 * lane);
  const float4 zv = *(const float4*)(z + (size_t)tok * DDIM + 4 * lane);
  float4 q;
  q.x = zv.x + (c.x - zv.x);
  q.y = zv.y + (c.y - zv.y);
  q.z = zv.z + (c.z - zv.z);
  q.w = zv.w + (c.w - zv.w);
  const size_t o = (size_t)tok * DDIM + 4 * lane;
  *(float4*)(out + OUT_ZQ  + o) = q;
  *(float4*)(out + OUT_EMB + o) = c;
  const float dx = q.x - zv.x, dy = q.y - zv.y, dz = q.z - zv.z, dw = q.w - zv.w;
  float s = dx * dx + dy * dy + dz * dz + dw * dw;
  #pragma unroll
  for (int o2 = 32; o2 > 0; o2 >>= 1) s += __shfl_down(s, o2);
  if (lane == 0) {
    cred[wv] = s;
    atomicAdd(&hist[bi], 1.0f);
    out[OUT_IDX + tok] = (float)bi;
  }
  __syncthreads();
  if (threadIdx.x == 0)
    atomicAdd(comm, (cred[0] + cred[1]) + (cred[2] + cred[3]));
}

// ---------------- scalars ----------------
__global__ __launch_bounds__(1024) void k_scal(const float* __restrict__ cu,
                                               const float* __restrict__ hist,
                                               const float* __restrict__ comm,
                                               float* __restrict__ out) {
  __shared__ float red[1024];
  const int tid = threadIdx.x;
  float us[4];
  float s = 0.0f;
  #pragma unroll
  for (int j = 0; j < 4; ++j) {
    const int k = tid * 4 + j;
    us[j] = cu[k] * 0.99f + hist[k];
    s += us[j];
  }
  red[tid] = s; __syncthreads();
  for (int o = 512; o > 0; o >>= 1) {
    if (tid < o) red[tid] += red[tid + o];
    __syncthreads();
  }
  const float usum = red[0];
  __syncthreads();
  float e = 0.0f;
  #pragma unroll
  for (int j = 0; j < 4; ++j) {
    const float p = (usum > 0.0f) ? (us[j] / (usum + GEPS)) : (1.0f / (float)KCB);
    e -= p * logf(p + GEPS);
  }
  red[tid] = e; __syncthreads();
  for (int o = 512; o > 0; o >>= 1) {
    if (tid < o) red[tid] += red[tid + o];
    __syncthreads();
  }
  if (tid == 0) {
    const float entropy = red[0];
    out[OUT_SCAL + 0] = comm[0] / (float)((size_t)NTOK * DDIM);
    out[OUT_SCAL + 1] = expf(entropy);
    out[OUT_SCAL + 2] = entropy;
  }
}

extern "C" void kernel_launch(void* const* d_in, const int* in_sizes, int n_in,
                              void* d_out, int out_size, void* d_ws, size_t ws_size,
                              hipStream_t stream) {
  const float* z  = (const float*)d_in[0];
  const float* u  = (const float*)d_in[1];
  const float* cb = (const float*)d_in[2];
  const float* cu = (const float*)d_in[3];

  float* ws   = (float*)d_ws;
  float* esq  = ws + WS_ESQ;
  float* zsq  = ws + WS_ZSQ;
  float* keyf = ws + WS_KEY;
  unsigned long long* key = (unsigned long long*)keyf;
  float* hist = ws + WS_HIST;
  float* comm = ws + WS_COMM;
  float* out  = (float*)d_out;

  if (ws_size >= (size_t)WS_END * 4) {
    unsigned short* zh = (unsigned short*)(ws + WS_ZH);
    k_prep<<<dim3((KCB + NTOK) / 64), dim3(256), 0, stream>>>(
        cb, z, esq, zsq, keyf, hist, comm, zh);
    k_mfma<<<dim3(2048), dim3(256), 0, stream>>>(zh, u, esq, zsq, key);
  } else {
    k_prep<<<dim3((KCB + NTOK) / 64), dim3(256), 0, stream>>>(
        cb, z, esq, zsq, keyf, hist, comm, (unsigned short*)nullptr);
    k_score<<<dim3(NTOK / BT, KCB / BK), dim3(256), 0, stream>>>(z, u, cb, esq, zsq, key);
  }

  k_final<<<dim3(NTOK / 4), dim3(256), 0, stream>>>(z, cb, key, out, hist, comm);
  k_scal <<<dim3(1), dim3(1024), 0, stream>>>(cu, hist, comm, out);
}

// Round 17
// 162.908 us; speedup vs baseline: 1.5617x; 1.0853x over previous
//
#include <hip/hip_runtime.h>
#include <math.h>

#define NTOK 8192
#define DDIM 256
#define KCB  4096
#define GEPS 1e-10f

typedef __attribute__((ext_vector_type(8))) short short8;   // 8 bf16 (4 VGPR)
typedef __attribute__((ext_vector_type(8))) unsigned short ushort8;
typedef __attribute__((ext_vector_type(4))) float f32x4;

// ws layout (float units)
#define WS_ESQ  0
#define WS_ZSQ  (WS_ESQ + KCB)          // 4096
#define WS_KEY  (WS_ZSQ + NTOK)         // 12288 (u64[8192])
#define WS_HIST (WS_KEY + 2 * NTOK)     // 28672
#define WS_COMM (WS_HIST + KCB)         // 32768
#define WS_ZH   32776                   // 16B-aligned
#define WS_END  (WS_ZH + (3 * NTOK * DDIM + 3 * KCB * DDIM) / 2)   // ≈ 19.01 MB

// plane strides/bases in USHORT units; K-step tiled layout:
// off = plane_base + kk*(NR*32) + r*32 + ss*8, ss = dh ^ ((r>>2)&3) baked in
#define PO_Z  (NTOK * DDIM)     // per-z-plane stride
#define PO_C  (KCB * DDIM)      // per-cb-plane stride
#define PO_CB (3 * NTOK * DDIM) // first cb plane

// out offsets (f32): z_q, embedding, indices, commitment, perplexity, entropy
#define OUT_ZQ   0
#define OUT_EMB  (NTOK * DDIM)
#define OUT_IDX  (2 * NTOK * DDIM)
#define OUT_SCAL (2 * NTOK * DDIM + NTOK)

__device__ __forceinline__ unsigned short f2bf(float x) {   // RNE f32->bf16
  unsigned int u = __float_as_uint(x);
  u += 0x7FFFu + ((u >> 16) & 1u);
  return (unsigned short)(u >> 16);
}
__device__ __forceinline__ float bf2f(unsigned short h) {
  return __uint_as_float(((unsigned int)h) << 16);
}

__device__ __forceinline__ void gload16(const void* g, void* l) {
  __builtin_amdgcn_global_load_lds(
      (const __attribute__((address_space(1))) unsigned int*)g,
      (__attribute__((address_space(3))) unsigned int*)l, 16, 0, 0);
}

// ---------------- prep: e_sq/z_sq + K-tiled plane split (coalesced, R15/R16) ----------------
// grid 192 x 256: block = 64 rows (4 waves x 16 rows). Per (plane,kk) each wave
// writes one fully-contiguous 1KB run (lane l -> row r0+(l>>2), slot l&3).
__global__ __launch_bounds__(256) void k_prep(const float* __restrict__ cb,
                                              const float* __restrict__ z,
                                              float* __restrict__ esq,
                                              float* __restrict__ zsq,
                                              float* __restrict__ keyf,
                                              float* __restrict__ hist,
                                              float* __restrict__ comm,
                                              unsigned short* __restrict__ zh) {
  const int l   = threadIdx.x & 63;
  const int wid = threadIdx.x >> 6;
  const int r0  = blockIdx.x * 64 + wid * 16;       // wave-uniform, 16-aligned
  const int rl  = r0 + (l >> 2);                    // this lane's row (0..12287)
  const bool isc = rl < KCB;                        // whole wave same side
  const int r_in  = isc ? rl : rl - KCB;
  const int r0_in = isc ? r0 : r0 - KCB;
  const float* src = isc ? (cb + (size_t)rl * DDIM) : (z + (size_t)r_in * DDIM);
  const int ss = l & 3;
  const int dh = ss ^ ((r_in >> 2) & 3);            // bank-deswizzle baked in
  const unsigned NR      = isc ? (unsigned)KCB : (unsigned)NTOK;
  const unsigned pbase   = isc ? (unsigned)PO_CB : 0u;
  const unsigned pstride = isc ? (unsigned)PO_C : (unsigned)PO_Z;

  float ssum = 0.0f;
  #pragma unroll
  for (int kk = 0; kk < 8; ++kk) {
    const float4 va = *(const float4*)(src + kk * 32 + dh * 8);
    const float4 vb = *(const float4*)(src + kk * 32 + dh * 8 + 4);
    ssum += va.x * va.x + va.y * va.y + va.z * va.z + va.w * va.w
          + vb.x * vb.x + vb.y * vb.y + vb.z * vb.z + vb.w * vb.w;
    if (zh) {
      const float vv[8] = {va.x, va.y, va.z, va.w, vb.x, vb.y, vb.z, vb.w};
      ushort8 h8, m8, l8;
      #pragma unroll
      for (int e = 0; e < 8; ++e) {
        const float x  = vv[e];
        const unsigned short h = f2bf(x);
        const float r1 = x - bf2f(h);
        const unsigned short m = f2bf(r1);
        const float r2 = r1 - bf2f(m);
        h8[e] = h; m8[e] = m; l8[e] = f2bf(r2);
      }
      const unsigned off = pbase + (unsigned)kk * NR * 32 + (unsigned)r0_in * 32
                         + (unsigned)l * 8;          // 64 lanes -> 1KB contiguous
      *(ushort8*)(zh + off)                = h8;
      *(ushort8*)(zh + off + pstride)      = m8;
      *(ushort8*)(zh + off + 2 * pstride)  = l8;
    }
  }
  ssum += __shfl_xor(ssum, 1);
  ssum += __shfl_xor(ssum, 2);
  if ((l & 3) == 0) {
    if (isc) esq[rl] = ssum;
    else     zsq[r_in] = ssum;
  }

  const int gid = blockIdx.x * 256 + threadIdx.x;   // 49152 >= 16384+4096+1
  if (gid < 2 * NTOK) keyf[gid] = 0.0f;
  else if (gid < 2 * NTOK + KCB) hist[gid - 2 * NTOK] = 0.0f;
  else if (gid == 2 * NTOK + KCB) comm[0] = 0.0f;
}

// ---------------- LDS-staged split-bf16 MFMA GEMM (R14 exact: 2-barrier, 3 blk/CU) ----------------
// 1-D grid 2048, 256 threads = 4 waves (2x2), tile 128x128, BK=32, 48KB LDS,
// 3 blocks/CU. Staging: 48 x 1KB fully-contiguous global runs (K-tiled planes).
__global__ __launch_bounds__(256, 3) void k_mfma(const unsigned short* __restrict__ zh,
                                                 const float* __restrict__ u,
                                                 const float* __restrict__ esq,
                                                 const float* __restrict__ zsq,
                                                 unsigned long long* __restrict__ key) {
  __shared__ __align__(1024) unsigned char lbuf[49152];

  const int tid = threadIdx.x;
  const int l   = tid & 63;
  const int wid = tid >> 6;

  // bijective XCD-compact swizzle (2048 % 8 == 0)
  const int bid = blockIdx.x;
  const int s   = (bid & 7) * 256 + (bid >> 3);   // contiguous 256-block chunk per XCD
  const int cx  = ((s >> 8) << 2) + (s & 3);      // code tile 0..31
  const int cy  = (s & 255) >> 2;                 // token tile 0..63
  const int tok0 = cy * 128;
  const int c0   = cx * 128;

  const int lrow = l & 15;
  const int lkg  = l >> 4;                  // 0..3
  const int tw = (wid >> 1) * 64;           // wave token base
  const int cw = (wid & 1) * 64;            // wave code base

  // staging: chunk c = wid + 4j; j<6 -> A, j>=6 -> B. Each chunk = 1KB
  // contiguous in ws (16 rows x 32 d, swizzle pre-baked); LDS dest linear.
  unsigned int srcoff[12], lbase[12];
  #pragma unroll
  for (int j = 0; j < 12; ++j) {
    const int c = wid + 4 * j;
    unsigned int off, lb;
    if (j < 6) {                            // A: 3 planes x 8 subtiles
      const int p = c >> 3, sub = c & 7;
      off = (unsigned)p * PO_Z + (unsigned)tok0 * 32 + (unsigned)sub * 512;
      lb  = (unsigned)(p * 8192 + sub * 1024);
    } else {                                // B: 3 planes x 8 subtiles
      const int q = c - 24;
      const int p = q >> 3, sub = q & 7;
      off = (unsigned)PO_CB + (unsigned)p * PO_C + (unsigned)c0 * 32
          + (unsigned)sub * 512;
      lb  = (unsigned)(24576 + p * 8192 + sub * 1024);
    }
    srcoff[j] = off + (unsigned)l * 8;
    lbase[j]  = lb;
  }

  f32x4 acc[4][4] = {};
  const unsigned int sw = ((unsigned int)(lkg ^ ((lrow >> 2) & 3))) << 4;
  const int rb = lkg * 4;

  for (int kk = 0; kk < 8; ++kk) {
    const unsigned int ka = (unsigned)kk * (NTOK * 32);
    const unsigned int kb = (unsigned)kk * (KCB * 32);
    __syncthreads();                        // previous step fully consumed
    #pragma unroll
    for (int j = 0; j < 6; ++j)  gload16(zh + srcoff[j] + ka, lbuf + lbase[j]);
    #pragma unroll
    for (int j = 6; j < 12; ++j) gload16(zh + srcoff[j] + kb, lbuf + lbase[j]);
    __syncthreads();                        // vmcnt drain; co-resident blocks overlap

    short8 bfr[3][4];
    #pragma unroll
    for (int ni = 0; ni < 4; ++ni) {
      const unsigned int boff = (unsigned int)(cw + ni * 16 + lrow) * 64 + sw;
      bfr[0][ni] = *(const short8*)(lbuf + 24576 + boff);   // bh
      bfr[1][ni] = *(const short8*)(lbuf + 32768 + boff);   // bm
      bfr[2][ni] = *(const short8*)(lbuf + 40960 + boff);   // bl
    }
    #pragma unroll
    for (int mi = 0; mi < 4; ++mi) {
      const unsigned int aoff = (unsigned int)(tw + mi * 16 + lrow) * 64 + sw;
      const short8 ah = *(const short8*)(lbuf + 0     + aoff);
      const short8 am = *(const short8*)(lbuf + 8192  + aoff);
      const short8 al = *(const short8*)(lbuf + 16384 + aoff);
      #pragma unroll
      for (int ni = 0; ni < 4; ++ni) {
        f32x4 a = acc[mi][ni];
        a = __builtin_amdgcn_mfma_f32_16x16x32_bf16(am, bfr[1][ni], a, 0, 0, 0); // mm
        a = __builtin_amdgcn_mfma_f32_16x16x32_bf16(ah, bfr[2][ni], a, 0, 0, 0); // hl
        a = __builtin_amdgcn_mfma_f32_16x16x32_bf16(al, bfr[0][ni], a, 0, 0, 0); // lh
        a = __builtin_amdgcn_mfma_f32_16x16x32_bf16(ah, bfr[1][ni], a, 0, 0, 0); // hm
        a = __builtin_amdgcn_mfma_f32_16x16x32_bf16(am, bfr[0][ni], a, 0, 0, 0); // mh
        a = __builtin_amdgcn_mfma_f32_16x16x32_bf16(ah, bfr[0][ni], a, 0, 0, 0); // hh
        acc[mi][ni] = a;
      }
    }
  }

  // ---- epilogue: gumbel + score + argmax. C/D: col=l&15, row=(l>>4)*4+reg ----
  float esv[4];
  #pragma unroll
  for (int ni = 0; ni < 4; ++ni) esv[ni] = esq[c0 + cw + ni * 16 + lrow];

  #pragma unroll
  for (int mi = 0; mi < 4; ++mi) {
    #pragma unroll
    for (int r = 0; r < 4; ++r) {
      const int t  = tok0 + tw + mi * 16 + rb + r;
      const float zq = zsq[t];
      float bv = -3.402823e38f;
      int   bc = c0 + cw + lrow;
      #pragma unroll
      for (int ni = 0; ni < 4; ++ni) {
        const int c = c0 + cw + ni * 16 + lrow;
        const float uu = u[(size_t)t * KCB + c];
        const float g  = -logf(-logf(uu + GEPS) + GEPS);
        const float sc = -((zq + esv[ni]) - 2.0f * acc[mi][ni][r]) + g;
        if (sc > bv) { bv = sc; bc = c; }        // ni ascending = code ascending
      }
      #pragma unroll
      for (int m = 1; m < 16; m <<= 1) {
        const float ov = __shfl_xor(bv, m);
        const int   oc = __shfl_xor(bc, m);
        if (ov > bv || (ov == bv && oc < bc)) { bv = ov; bc = oc; }
      }
      if (lrow == 0) {
        unsigned int b = __float_as_uint(bv);
        b = (b & 0x80000000u) ? ~b : (b | 0x80000000u);
        const unsigned long long kk2 =
            ((unsigned long long)b << 32) | (unsigned int)(KCB - 1 - bc);
        atomicMax(&key[t], kk2);
      }
    }
  }
}

// ---------------- fallback f32 path (used only if ws too small) ----------------
#define BT 128
#define BK 128
#define DC 32
#define PS 132
__global__ __launch_bounds__(256) void k_score(const float* __restrict__ z,
                                               const float* __restrict__ u,
                                               const float* __restrict__ cb,
                                               const float* __restrict__ esq,
                                               const float* __restrict__ zsq,
                                               unsigned long long* __restrict__ key) {
  __shared__ float zsm[DC][PS];
  __shared__ float csm[DC][PS];
  const int tid  = threadIdx.x;
  const int tok0 = blockIdx.x * BT;
  const int kb   = blockIdx.y * BK;
  const int tx = tid & 15;
  const int ty = tid >> 4;
  const int srow = tid >> 3;
  const int sc4  = (tid & 7) * 4;
  float acc[8][8] = {};
  float4 zr[4], cr[4];
  #pragma unroll
  for (int j = 0; j < 4; ++j) {
    const int r = srow + 32 * j;
    zr[j] = *(const float4*)(z  + (size_t)(tok0 + r) * DDIM + sc4);
    cr[j] = *(const float4*)(cb + (size_t)(kb  + r) * DDIM + sc4);
  }
  for (int dc = 0; dc < DDIM / DC; ++dc) {
    __syncthreads();
    #pragma unroll
    for (int j = 0; j < 4; ++j) {
      const int r = srow + 32 * j;
      zsm[sc4 + 0][r] = zr[j].x; zsm[sc4 + 1][r] = zr[j].y;
      zsm[sc4 + 2][r] = zr[j].z; zsm[sc4 + 3][r] = zr[j].w;
      csm[sc4 + 0][r] = cr[j].x; csm[sc4 + 1][r] = cr[j].y;
      csm[sc4 + 2][r] = cr[j].z; csm[sc4 + 3][r] = cr[j].w;
    }
    __syncthreads();
    if (dc + 1 < DDIM / DC) {
      const int d0 = (dc + 1) * DC;
      #pragma unroll
      for (int j = 0; j < 4; ++j) {
        const int r = srow + 32 * j;
        zr[j] = *(const float4*)(z  + (size_t)(tok0 + r) * DDIM + d0 + sc4);
        cr[j] = *(const float4*)(cb + (size_t)(kb  + r) * DDIM + d0 + sc4);
      }
    }
    #pragma unroll 4
    for (int d = 0; d < DC; ++d) {
      const float4 za = *(const float4*)&zsm[d][8 * ty];
      const float4 zb = *(const float4*)&zsm[d][8 * ty + 4];
      const float4 ca = *(const float4*)&csm[d][8 * tx];
      const float4 cc = *(const float4*)&csm[d][8 * tx + 4];
      const float zf[8] = {za.x, za.y, za.z, za.w, zb.x, zb.y, zb.z, zb.w};
      const float cf[8] = {ca.x, ca.y, ca.z, ca.w, cc.x, cc.y, cc.z, cc.w};
      #pragma unroll
      for (int i = 0; i < 8; ++i)
        #pragma unroll
        for (int j = 0; j < 8; ++j) acc[i][j] += zf[i] * cf[j];
    }
  }
  const float4 ea = *(const float4*)(esq + kb + 8 * tx);
  const float4 eb = *(const float4*)(esq + kb + 8 * tx + 4);
  const float esa[8] = {ea.x, ea.y, ea.z, ea.w, eb.x, eb.y, eb.z, eb.w};
  float bv[8]; int bj[8];
  #pragma unroll
  for (int i = 0; i < 8; ++i) {
    const int tok = tok0 + 8 * ty + i;
    const float zq = zsq[tok];
    const float4 ua = *(const float4*)(u + (size_t)tok * KCB + kb + 8 * tx);
    const float4 ub = *(const float4*)(u + (size_t)tok * KCB + kb + 8 * tx + 4);
    const float uu[8] = {ua.x, ua.y, ua.z, ua.w, ub.x, ub.y, ub.z, ub.w};
    bv[i] = -3.402823e38f; bj[i] = kb + 8 * tx;
    #pragma unroll
    for (int j = 0; j < 8; ++j) {
      const float g = -logf(-logf(uu[j] + GEPS) + GEPS);
      const float s = -((zq + esa[j]) - 2.0f * acc[i][j]) + g;
      if (s > bv[i]) { bv[i] = s; bj[i] = kb + 8 * tx + j; }
    }
  }
  __syncthreads();
  float* pv = &zsm[0][0];
  int*   pi = (int*)&csm[0][0];
  #pragma unroll
  for (int i = 0; i < 8; ++i) {
    pv[(8 * ty + i) * 16 + tx] = bv[i];
    pi[(8 * ty + i) * 16 + tx] = bj[i];
  }
  __syncthreads();
  if (tid < BT) {
    float best  = pv[tid * 16];
    int   besti = pi[tid * 16];
    for (int x = 1; x < 16; ++x) {
      const float v = pv[tid * 16 + x];
      if (v > best) { best = v; besti = pi[tid * 16 + x]; }
    }
    unsigned int b = __float_as_uint(best);
    b = (b & 0x80000000u) ? ~b : (b | 0x80000000u);
    const unsigned long long kk =
        ((unsigned long long)b << 32) | (unsigned int)(KCB - 1 - besti);
    atomicMax(&key[tok0 + tid], kk);
  }
}

// ---------------- finalize per token (R16: block-reduced comm atomics) ----------------
__global__ __launch_bounds__(256) void k_final(const float* __restrict__ z,
                                               const float* __restrict__ cb,
                                               const unsigned long long* __restrict__ key,
                                               float* __restrict__ out,
                                               float* __restrict__ hist,
                                               float* __restrict__ comm) {
  __shared__ float cred[4];
  const int lane = threadIdx.x & 63;
  const int wv   = threadIdx.x >> 6;
  const int tok  = blockIdx.x * 4 + wv;
  const unsigned long long kk = key[tok];
  int bi = KCB - 1 - (int)(kk & 0xFFFFFFFFu);
  bi = min(max(bi, 0), KCB - 1);
  const float4 c  = *(const float4*)(cb + (size_t)bi * DDIM + 4 * lane);
  const float4 zv = *(const float4*)(z + (size_t)tok * DDIM + 4 * lane);
  float4 q;
  q.x = zv.x + (c.x - zv.x);
  q.y = zv.y + (c.y - zv.y);
  q.z = zv.z + (c.z - zv.z);
  q.w = zv.w + (c.w - zv.w);
  const size_t o = (size_t)tok * DDIM + 4 * lane;
  *(float4*)(out + OUT_ZQ  + o) = q;
  *(float4*)(out + OUT_EMB + o) = c;
  const float dx = q.x - zv.x, dy = q.y - zv.y, dz = q.z - zv.z, dw = q.w - zv.w;
  float s = dx * dx + dy * dy + dz * dz + dw * dw;
  #pragma unroll
  for (int o2 = 32; o2 > 0; o2 >>= 1) s += __shfl_down(s, o2);
  if (lane == 0) {
    cred[wv] = s;
    atomicAdd(&hist[bi], 1.0f);
    out[OUT_IDX + tok] = (float)bi;
  }
  __syncthreads();
  if (threadIdx.x == 0)
    atomicAdd(comm, (cred[0] + cred[1]) + (cred[2] + cred[3]));
}

// ---------------- scalars ----------------
__global__ __launch_bounds__(1024) void k_scal(const float* __restrict__ cu,
                                               const float* __restrict__ hist,
                                               const float* __restrict__ comm,
                                               float* __restrict__ out) {
  __shared__ float red[1024];
  const int tid = threadIdx.x;
  float us[4];
  float s = 0.0f;
  #pragma unroll
  for (int j = 0; j < 4; ++j) {
    const int k = tid * 4 + j;
    us[j] = cu[k] * 0.99f + hist[k];
    s += us[j];
  }
  red[tid] = s; __syncthreads();
  for (int o = 512; o > 0; o >>= 1) {
    if (tid < o) red[tid] += red[tid + o];
    __syncthreads();
  }
  const float usum = red[0];
  __syncthreads();
  float e = 0.0f;
  #pragma unroll
  for (int j = 0; j < 4; ++j) {
    const float p = (usum > 0.0f) ? (us[j] / (usum + GEPS)) : (1.0f / (float)KCB);
    e -= p * logf(p + GEPS);
  }
  red[tid] = e; __syncthreads();
  for (int o = 512; o > 0; o >>= 1) {
    if (tid < o) red[tid] += red[tid + o];
    __syncthreads();
  }
  if (tid == 0) {
    const float entropy = red[0];
    out[OUT_SCAL + 0] = comm[0] / (float)((size_t)NTOK * DDIM);
    out[OUT_SCAL + 1] = expf(entropy);
    out[OUT_SCAL + 2] = entropy;
  }
}

extern "C" void kernel_launch(void* const* d_in, const int* in_sizes, int n_in,
                              void* d_out, int out_size, void* d_ws, size_t ws_size,
                              hipStream_t stream) {
  const float* z  = (const float*)d_in[0];
  const float* u  = (const float*)d_in[1];
  const float* cb = (const float*)d_in[2];
  const float* cu = (const float*)d_in[3];

  float* ws   = (float*)d_ws;
  float* esq  = ws + WS_ESQ;
  float* zsq  = ws + WS_ZSQ;
  float* keyf = ws + WS_KEY;
  unsigned long long* key = (unsigned long long*)keyf;
  float* hist = ws + WS_HIST;
  float* comm = ws + WS_COMM;
  float* out  = (float*)d_out;

  if (ws_size >= (size_t)WS_END * 4) {
    unsigned short* zh = (unsigned short*)(ws + WS_ZH);
    k_prep<<<dim3((KCB + NTOK) / 64), dim3(256), 0, stream>>>(
        cb, z, esq, zsq, keyf, hist, comm, zh);
    k_mfma<<<dim3(2048), dim3(256), 0, stream>>>(zh, u, esq, zsq, key);
  } else {
    k_prep<<<dim3((KCB + NTOK) / 64), dim3(256), 0, stream>>>(
        cb, z, esq, zsq, keyf, hist, comm, (unsigned short*)nullptr);
    k_score<<<dim3(NTOK / BT, KCB / BK), dim3(256), 0, stream>>>(z, u, cb, esq, zsq, key);
  }

  k_final<<<dim3(NTOK / 4), dim3(256), 0, stream>>>(z, cb, key, out, hist, comm);
  k_scal <<<dim3(1), dim3(1024), 0, stream>>>(cu, hist, comm, out);
}